// Round 5
// baseline (1063.987 us; speedup 1.0000x reference)
//
#include <hip/hip_runtime.h>
#include <math.h>

typedef __attribute__((ext_vector_type(8))) short bf16x8;
typedef __attribute__((ext_vector_type(4))) float f32x4;

#define Dd 256
#define Hh 1024
#define Kk 128
#define NSTEP 4
#define LDI 264    // in_bf row stride (bf16 elems)
#define LDH 1032   // hid row stride
#define LDY 260    // final-state fp32 row stride

static __device__ __forceinline__ unsigned short f2bf(float f) {
    unsigned u = __builtin_bit_cast(unsigned, f);
    unsigned r = (u + 0x7fffu + ((u >> 16) & 1u)) >> 16;   // RNE
    return (unsigned short)r;
}

static __device__ __forceinline__ float fast_tanh(float x) {
    const float e = __expf(2.0f * x);
    return 1.0f - 2.0f / (e + 1.0f);
}

// W[R][C] fp32 -> WT[C][R] bf16
__global__ void transpose_bf_kernel(const float* __restrict__ W,
                                    unsigned short* __restrict__ WT, int R, int C)
{
    int i = blockIdx.x * blockDim.x + threadIdx.x;
    if (i < R * C) {
        const int r = i / C, c = i % C;
        WT[(size_t)c * R + r] = f2bf(W[i]);
    }
}

// One block = 8 waves = 512 threads; 16 rows/block; grid 256; 2 blocks/CU.
// GEMM1: wave w owns hid cols [w*128,+128) (8 tiles). GEMM2: cols [w*32,+32) (2 tiles).
__global__ __launch_bounds__(512, 4) void ode_fused(
    const float* __restrict__ x,
    const unsigned short* __restrict__ W1T,   // [H][D] bf16
    const float* __restrict__ b1,
    const unsigned short* __restrict__ W2T,   // [D][H] bf16
    const float* __restrict__ b2,
    const int* __restrict__ indices,
    float* __restrict__ out)
{
    __shared__ __align__(16) unsigned short in_bf[16 * LDI];
    __shared__ __align__(16) unsigned short hid[16 * LDH];
    __shared__ float b1s[Hh];
    __shared__ float b2s[Dd];

    const int tid  = threadIdx.x;
    const int lane = tid & 63;
    const int w    = tid >> 6;      // wave 0..7
    const int quad = lane >> 4;
    const int l16  = lane & 15;
    const int row0 = blockIdx.x * 16;

    for (int i = tid; i < Hh; i += 512) b1s[i] = b1[i];
    for (int i = tid; i < Dd; i += 512) b2s[i] = b2[i];

    float yv[2][4];   // state: col = w*32 + ct*16 + l16, row = quad*4 + r
    float av[2][4];   // RK4 accumulator

#pragma unroll
    for (int ct = 0; ct < 2; ++ct) {
        const int col = w * 32 + ct * 16 + l16;
#pragma unroll
        for (int r = 0; r < 4; ++r) {
            const int row = quad * 4 + r;
            const float v = x[(size_t)(row0 + row) * Dd + col];
            yv[ct][r] = v;
            in_bf[row * LDI + col] = f2bf(v);
        }
    }
    __syncthreads();

    const float h  = 1.0f / NSTEP;
    const float h6 = h / 6.0f, h3 = h / 3.0f, h2 = h * 0.5f;

    const unsigned short* w1p = W1T + (size_t)(w * 128 + l16) * Dd + quad * 8;
    const unsigned short* w2p = W2T + (size_t)(w * 32 + l16) * Hh + quad * 8;

#pragma unroll 1
    for (int s = 0; s < NSTEP; ++s) {
#pragma unroll 1
        for (int e = 0; e < 4; ++e) {
            // ---- GEMM1: hid[16][w*128..+128] = tanh(in_bf @ W1 + b1)
            f32x4 acc[8] = {};
#pragma unroll
            for (int kh = 0; kh < 2; ++kh) {
                bf16x8 afr[4];
#pragma unroll
                for (int kst = 0; kst < 4; ++kst)
                    afr[kst] = *(const bf16x8*)(&in_bf[l16 * LDI + kh * 128 + kst * 32 + quad * 8]);
                bf16x8 bv[4];
#pragma unroll
                for (int kst = 0; kst < 4; ++kst)
                    bv[kst] = *(const bf16x8*)(w1p + kh * 128 + kst * 32);
#pragma unroll
                for (int ct = 0; ct < 8; ++ct) {
                    bf16x8 nb[4];
                    if (ct < 7) {
#pragma unroll
                        for (int kst = 0; kst < 4; ++kst)
                            nb[kst] = *(const bf16x8*)(w1p + (size_t)(ct + 1) * 16 * Dd + kh * 128 + kst * 32);
                    }
#pragma unroll
                    for (int kst = 0; kst < 4; ++kst)
                        acc[ct] = __builtin_amdgcn_mfma_f32_16x16x32_bf16(afr[kst], bv[kst], acc[ct], 0, 0, 0);
#pragma unroll
                    for (int kst = 0; kst < 4; ++kst) bv[kst] = nb[kst];
                }
            }
#pragma unroll
            for (int ct = 0; ct < 8; ++ct) {
                const int col = w * 128 + ct * 16 + l16;
                const float bb = b1s[col];
#pragma unroll
                for (int r = 0; r < 4; ++r)
                    hid[(quad * 4 + r) * LDH + col] = f2bf(fast_tanh(acc[ct][r] + bb));
            }
            __syncthreads();

            // ---- GEMM2: F[16][w*32..+32] = hid @ W2 + b2 ; RK4 update
            f32x4 acA[2] = {}, acB[2] = {};
#pragma unroll
            for (int kseg = 0; kseg < 4; ++kseg) {
                bf16x8 a2[8];
#pragma unroll
                for (int kst = 0; kst < 8; ++kst)
                    a2[kst] = *(const bf16x8*)(&hid[l16 * LDH + kseg * 256 + kst * 32 + quad * 8]);
#pragma unroll
                for (int ct = 0; ct < 2; ++ct) {
                    bf16x8 bv[8];
#pragma unroll
                    for (int kst = 0; kst < 8; ++kst)
                        bv[kst] = *(const bf16x8*)(w2p + (size_t)ct * 16 * Hh + kseg * 256 + kst * 32);
#pragma unroll
                    for (int kst = 0; kst < 4; ++kst)
                        acA[ct] = __builtin_amdgcn_mfma_f32_16x16x32_bf16(a2[kst], bv[kst], acA[ct], 0, 0, 0);
#pragma unroll
                    for (int kst = 4; kst < 8; ++kst)
                        acB[ct] = __builtin_amdgcn_mfma_f32_16x16x32_bf16(a2[kst], bv[kst], acB[ct], 0, 0, 0);
                }
            }
#pragma unroll
            for (int ct = 0; ct < 2; ++ct) {
                const int col = w * 32 + ct * 16 + l16;
                const float bb = b2s[col];
#pragma unroll
                for (int r = 0; r < 4; ++r) {
                    const float F = acA[ct][r] + acB[ct][r] + bb;
                    float tmp;
                    if (e == 0)      { av[ct][r] = yv[ct][r] + h6 * F; tmp = yv[ct][r] + h2 * F; }
                    else if (e == 1) { av[ct][r] += h3 * F;            tmp = yv[ct][r] + h2 * F; }
                    else if (e == 2) { av[ct][r] += h3 * F;            tmp = yv[ct][r] + h  * F; }
                    else             { yv[ct][r] = av[ct][r] + h6 * F; tmp = yv[ct][r]; }
                    in_bf[(quad * 4 + r) * LDI + col] = f2bf(tmp);
                }
            }
            __syncthreads();
        }
    }

    // final state -> LDS (reuse hid) -> gather
    float* yf = (float*)hid;
#pragma unroll
    for (int ct = 0; ct < 2; ++ct) {
        const int col = w * 32 + ct * 16 + l16;
#pragma unroll
        for (int r = 0; r < 4; ++r)
            yf[(quad * 4 + r) * LDY + col] = yv[ct][r];
    }
    __syncthreads();

    for (int i = tid; i < 16 * Kk; i += 512) {
        const int row = i >> 7;
        const int kc  = i & (Kk - 1);
        const int gi  = (row0 + row) * Kk + kc;
        out[gi] = yf[row * LDY + indices[gi]];
    }
}

extern "C" void kernel_launch(void* const* d_in, const int* in_sizes, int n_in,
                              void* d_out, int out_size, void* d_ws, size_t ws_size,
                              hipStream_t stream)
{
    const float* x  = (const float*)d_in[0];
    const float* W1 = (const float*)d_in[1];
    const float* b1 = (const float*)d_in[2];
    const float* W2 = (const float*)d_in[3];
    const float* b2 = (const float*)d_in[4];
    const int* indices = (const int*)d_in[5];
    float* out = (float*)d_out;

    const int H = in_sizes[2];        // 1024
    const int D = in_sizes[4];        // 256
    const int B = in_sizes[0] / D;    // 4096

    unsigned short* W1T = (unsigned short*)d_ws;                 // [H][D]
    unsigned short* W2T = W1T + (size_t)H * D;                   // [D][H]

    transpose_bf_kernel<<<(int)(((size_t)D * H + 255) / 256), 256, 0, stream>>>(W1, W1T, D, H);
    transpose_bf_kernel<<<(int)(((size_t)H * D + 255) / 256), 256, 0, stream>>>(W2, W2T, H, D);

    ode_fused<<<B / 16, 512, 0, stream>>>(x, W1T, b1, W2T, b2, indices, out);
}

// Round 6
// 344.806 us; speedup vs baseline: 3.0858x; 3.0858x over previous
//
#include <hip/hip_runtime.h>
#include <math.h>

typedef __attribute__((ext_vector_type(8))) short bf16x8;
typedef __attribute__((ext_vector_type(4))) float f32x4;

#define Dd 256
#define Hh 1024
#define Kk 128
#define NSTEP 2
#define LDI 264    // in_bf row stride (bf16 elems)
#define LDH 1032   // hid row stride
#define LDY 260    // final-state fp32 row stride

static __device__ __forceinline__ unsigned short f2bf(float f) {
    unsigned u = __builtin_bit_cast(unsigned, f);
    unsigned r = (u + 0x7fffu + ((u >> 16) & 1u)) >> 16;   // RNE
    return (unsigned short)r;
}

static __device__ __forceinline__ float fast_tanh(float x) {
    const float e = __expf(2.0f * x);
    return 1.0f - 2.0f / (e + 1.0f);
}

// W[R][C] fp32 -> WT[C][R] bf16
__global__ void transpose_bf_kernel(const float* __restrict__ W,
                                    unsigned short* __restrict__ WT, int R, int C)
{
    int i = blockIdx.x * blockDim.x + threadIdx.x;
    if (i < R * C) {
        const int r = i / C, c = i % C;
        WT[(size_t)c * R + r] = f2bf(W[i]);
    }
}

// One block = 16 waves = 1024 threads; 16 rows/block; grid 256 (1 block/CU).
// NO __launch_bounds__ (capping the arch-VGPR half of the unified file caused
// spills in R4/R5). Per-wave live set kept ~75 arch VGPRs by construction.
// GEMM1: wave w owns hid cols [w*64,+64) (4 tiles). GEMM2: cols [w*16,+16) (1 tile).
__global__ void ode_fused(
    const float* __restrict__ x,
    const unsigned short* __restrict__ W1T,   // [H][D] bf16
    const float* __restrict__ b1,
    const unsigned short* __restrict__ W2T,   // [D][H] bf16
    const float* __restrict__ b2,
    const int* __restrict__ indices,
    float* __restrict__ out)
{
    __shared__ __align__(16) unsigned short in_bf[16 * LDI];
    __shared__ __align__(16) unsigned short hid[16 * LDH];
    __shared__ float b1s[Hh];
    __shared__ float b2s[Dd];

    const int tid  = threadIdx.x;
    const int lane = tid & 63;
    const int w    = tid >> 6;      // wave 0..15
    const int quad = lane >> 4;
    const int l16  = lane & 15;
    const int row0 = blockIdx.x * 16;

    for (int i = tid; i < Hh; i += 1024) b1s[i] = b1[i];
    for (int i = tid; i < Dd; i += 1024) b2s[i] = b2[i];

    float yv[4];   // state: col = w*16 + l16, row = quad*4 + r
    float av[4];   // RK4 accumulator

    const int scol = w * 16 + l16;
#pragma unroll
    for (int r = 0; r < 4; ++r) {
        const int row = quad * 4 + r;
        const float v = x[(size_t)(row0 + row) * Dd + scol];
        yv[r] = v;
        in_bf[row * LDI + scol] = f2bf(v);
    }
    __syncthreads();

    const float h  = 1.0f / NSTEP;
    const float h6 = h / 6.0f, h3 = h / 3.0f, h2 = h * 0.5f;

    const unsigned short* w1p = W1T + (size_t)(w * 64 + l16) * Dd + quad * 8;
    const unsigned short* w2p = W2T + (size_t)(w * 16 + l16) * Hh + quad * 8;

#pragma unroll 1
    for (int s = 0; s < NSTEP; ++s) {
#pragma unroll 1
        for (int e = 0; e < 4; ++e) {
            // ---- GEMM1: hid[16][w*64..+64] = tanh(in_bf @ W1 + b1)
            f32x4 acc[4] = {};
#pragma unroll
            for (int kh = 0; kh < 2; ++kh) {
                bf16x8 afr[4];
#pragma unroll
                for (int kst = 0; kst < 4; ++kst)
                    afr[kst] = *(const bf16x8*)(&in_bf[l16 * LDI + kh * 128 + kst * 32 + quad * 8]);
#pragma unroll
                for (int ct = 0; ct < 4; ++ct) {
                    bf16x8 bv[4];
#pragma unroll
                    for (int kst = 0; kst < 4; ++kst)
                        bv[kst] = *(const bf16x8*)(w1p + (size_t)ct * 16 * Dd + kh * 128 + kst * 32);
#pragma unroll
                    for (int kst = 0; kst < 4; ++kst)
                        acc[ct] = __builtin_amdgcn_mfma_f32_16x16x32_bf16(afr[kst], bv[kst], acc[ct], 0, 0, 0);
                }
            }
#pragma unroll
            for (int ct = 0; ct < 4; ++ct) {
                const int col = w * 64 + ct * 16 + l16;
                const float bb = b1s[col];
#pragma unroll
                for (int r = 0; r < 4; ++r)
                    hid[(quad * 4 + r) * LDH + col] = f2bf(fast_tanh(acc[ct][r] + bb));
            }
            __syncthreads();

            // ---- GEMM2: F[16][w*16..+16] = hid @ W2 + b2 ; RK4 update
            f32x4 acA = {0.f, 0.f, 0.f, 0.f}, acB = {0.f, 0.f, 0.f, 0.f};
#pragma unroll
            for (int kseg = 0; kseg < 8; ++kseg) {
                bf16x8 a2[4], bv[4];
#pragma unroll
                for (int kst = 0; kst < 4; ++kst) {
                    a2[kst] = *(const bf16x8*)(&hid[l16 * LDH + kseg * 128 + kst * 32 + quad * 8]);
                    bv[kst] = *(const bf16x8*)(w2p + kseg * 128 + kst * 32);
                }
                acA = __builtin_amdgcn_mfma_f32_16x16x32_bf16(a2[0], bv[0], acA, 0, 0, 0);
                acB = __builtin_amdgcn_mfma_f32_16x16x32_bf16(a2[1], bv[1], acB, 0, 0, 0);
                acA = __builtin_amdgcn_mfma_f32_16x16x32_bf16(a2[2], bv[2], acA, 0, 0, 0);
                acB = __builtin_amdgcn_mfma_f32_16x16x32_bf16(a2[3], bv[3], acB, 0, 0, 0);
            }
            {
                const float bb = b2s[scol];
#pragma unroll
                for (int r = 0; r < 4; ++r) {
                    const float F = acA[r] + acB[r] + bb;
                    float tmp;
                    if (e == 0)      { av[r] = yv[r] + h6 * F; tmp = yv[r] + h2 * F; }
                    else if (e == 1) { av[r] += h3 * F;        tmp = yv[r] + h2 * F; }
                    else if (e == 2) { av[r] += h3 * F;        tmp = yv[r] + h  * F; }
                    else             { yv[r] = av[r] + h6 * F; tmp = yv[r]; }
                    in_bf[(quad * 4 + r) * LDI + scol] = f2bf(tmp);
                }
            }
            __syncthreads();
        }
    }

    // final state -> LDS (reuse hid) -> gather
    float* yf = (float*)hid;
#pragma unroll
    for (int r = 0; r < 4; ++r)
        yf[(quad * 4 + r) * LDY + scol] = yv[r];
    __syncthreads();

    for (int i = tid; i < 16 * Kk; i += 1024) {
        const int row = i >> 7;
        const int kc  = i & (Kk - 1);
        const int gi  = (row0 + row) * Kk + kc;
        out[gi] = yf[row * LDY + indices[gi]];
    }
}

extern "C" void kernel_launch(void* const* d_in, const int* in_sizes, int n_in,
                              void* d_out, int out_size, void* d_ws, size_t ws_size,
                              hipStream_t stream)
{
    const float* x  = (const float*)d_in[0];
    const float* W1 = (const float*)d_in[1];
    const float* b1 = (const float*)d_in[2];
    const float* W2 = (const float*)d_in[3];
    const float* b2 = (const float*)d_in[4];
    const int* indices = (const int*)d_in[5];
    float* out = (float*)d_out;

    const int H = in_sizes[2];        // 1024
    const int D = in_sizes[4];        // 256
    const int B = in_sizes[0] / D;    // 4096

    unsigned short* W1T = (unsigned short*)d_ws;                 // [H][D]
    unsigned short* W2T = W1T + (size_t)H * D;                   // [D][H]

    transpose_bf_kernel<<<(int)(((size_t)D * H + 255) / 256), 256, 0, stream>>>(W1, W1T, D, H);
    transpose_bf_kernel<<<(int)(((size_t)H * D + 255) / 256), 256, 0, stream>>>(W2, W2T, H, D);

    ode_fused<<<B / 16, 1024, 0, stream>>>(x, W1T, b1, W2T, b2, indices, out);
}